// Round 2
// baseline (33736.279 us; speedup 1.0000x reference)
//
#include <hip/hip_runtime.h>
#include <math.h>

// Problem constants (AttnDecoderRNN): H=1024 hidden, V=16000 vocab, B=64 batch,
// L=256 enc len, T=128 decoder steps.
#define HH 1024
#define VV 16000
#define BB 64
#define LL 256
#define TT 128

#define NBLK 256  // k_loop grid: one block per CU; all co-resident

// ---------------------------------------------------------------------------
// Workspace layout (floats):
//   H_all  [T][B][H]   : h_t for every step (feeds the big output GEMM)
//   xin    [B][2H]     : e | ctx   (input to comb GEMM)
//   x_acc  [B][H]      : comb GEMM accumulator (bias+relu applied by consumer)
//   gates  [B][4H]     : gates GEMM accumulator (i,f,g,o)
//   h_buf  [B][H]
//   c0,c1  [B][H]      : double-buffered cell state
//   sc_all [B][L]      : raw attention scores (pre-softmax), cross-block
//   bar    [2048 u32]  : software grid barrier state (memset 0 each launch)
// ---------------------------------------------------------------------------

// Software grid barrier, multi-XCD safe:
//  - agent-scope atomics (MALL coherence point; per-XCD L2 never trusted)
//  - __threadfence() = agent fence -> L2 writeback/invalidate on gfx950, so
//    plain global stores before the barrier are visible after it
//  - two-level arrival: 16 groups x 16 blocks, padded counters
// Layout: bar[0]=gen, bar[64+64g]=group counters (g<16), bar[1536]=root.
__device__ __forceinline__ void grid_barrier(unsigned* bar)
{
    __syncthreads();
    if (threadIdx.x == 0) {
        __threadfence();  // release: push this block's writes to coherence pt
        unsigned* gen = bar;
        unsigned* gcnt = bar + 64 + (blockIdx.x >> 4) * 64;
        unsigned* root = bar + 1536;
        const unsigned g =
            __hip_atomic_load(gen, __ATOMIC_RELAXED, __HIP_MEMORY_SCOPE_AGENT);
        bool releaser = false;
        if (__hip_atomic_fetch_add(gcnt, 1u, __ATOMIC_ACQ_REL,
                                   __HIP_MEMORY_SCOPE_AGENT) == 15u) {
            __hip_atomic_store(gcnt, 0u, __ATOMIC_RELAXED,
                               __HIP_MEMORY_SCOPE_AGENT);
            if (__hip_atomic_fetch_add(root, 1u, __ATOMIC_ACQ_REL,
                                       __HIP_MEMORY_SCOPE_AGENT) == 15u) {
                __hip_atomic_store(root, 0u, __ATOMIC_RELAXED,
                                   __HIP_MEMORY_SCOPE_AGENT);
                __hip_atomic_store(gen, g + 1u, __ATOMIC_RELEASE,
                                   __HIP_MEMORY_SCOPE_AGENT);
                releaser = true;
            }
        }
        if (!releaser) {
            while (__hip_atomic_load(gen, __ATOMIC_ACQUIRE,
                                     __HIP_MEMORY_SCOPE_AGENT) == g)
                __builtin_amdgcn_s_sleep(1);
        }
        __threadfence();  // acquire: invalidate stale L1/L2 lines
    }
    __syncthreads();
}

__device__ __forceinline__ float sigm(float x) { return 1.0f / (1.0f + expf(-x)); }

// Full-width LSTM for one batch row: every thread handles 4 of the 1024 lanes.
// All sibling blocks compute identical results; only `writer` stores globals.
__device__ __forceinline__ void lstm_full(
    const float* __restrict__ gates_acc, const float* __restrict__ b_ih,
    const float* __restrict__ b_hh, const float* __restrict__ c_rd,
    float* __restrict__ c_wr, float* __restrict__ h_buf,
    float* __restrict__ Hall_t, float* h_s, int b, int tid, bool first_c,
    bool writer)
{
    const int j = tid * 4;
    const float* gb = gates_acc + (size_t)b * 4 * HH;
    float4 gi = *(const float4*)(gb + j);
    float4 gf = *(const float4*)(gb + HH + j);
    float4 gg = *(const float4*)(gb + 2 * HH + j);
    float4 go = *(const float4*)(gb + 3 * HH + j);
    float4 bii = *(const float4*)(b_ih + j),          bhi = *(const float4*)(b_hh + j);
    float4 bif_ = *(const float4*)(b_ih + HH + j),    bhf = *(const float4*)(b_hh + HH + j);
    float4 big = *(const float4*)(b_ih + 2 * HH + j), bhg = *(const float4*)(b_hh + 2 * HH + j);
    float4 bio = *(const float4*)(b_ih + 3 * HH + j), bho = *(const float4*)(b_hh + 3 * HH + j);
    float4 co = first_c ? make_float4(0.f, 0.f, 0.f, 0.f)
                        : *(const float4*)(c_rd + (size_t)b * HH + j);
    float4 cn, hn;
#define DO_LSTM(X)                                        \
    {                                                     \
        float iv = sigm(gi.X + bii.X + bhi.X);            \
        float fv = sigm(gf.X + bif_.X + bhf.X);           \
        float gv = tanhf(gg.X + big.X + bhg.X);           \
        float ov = sigm(go.X + bio.X + bho.X);            \
        float c2 = fv * co.X + iv * gv;                   \
        cn.X = c2;                                        \
        hn.X = ov * tanhf(c2);                            \
    }
    DO_LSTM(x) DO_LSTM(y) DO_LSTM(z) DO_LSTM(w)
#undef DO_LSTM
    if (writer) {
        *(float4*)(c_wr + (size_t)b * HH + j) = cn;
        *(float4*)(h_buf + (size_t)b * HH + j) = hn;
        *(float4*)(Hall_t + (size_t)b * HH + j) = hn;
    }
    if (h_s) *(float4*)(h_s + j) = hn;
}

// ---------------------------------------------------------------------------
// Shared fp32 GEMM tile core: C[64 x 64] partial over k-range, atomicAdd out.
// A is [64][lda] row-major; W is [N][ldw] row-major (so C = A @ W^T).
// If RELU_BIAS: A element (b,k) -> relu(A[b][k] + abias[k]).
// Register-prefetch double buffering: next k-tile's global loads issue right
// after the post-store barrier so their latency hides under the 32-k FMA loop.
// ---------------------------------------------------------------------------
template <bool RELU_BIAS>
__device__ __forceinline__ void gemm64x64(
    const float* __restrict__ A, int lda, const float* __restrict__ abias,
    const float* __restrict__ Wm, int ldw, int n0, int k0, int klen,
    float* __restrict__ Cacc, int ldc, float* __restrict__ smem)
{
    float (*As)[68] = (float (*)[68])smem;
    float (*Ws)[68] = (float (*)[68])(smem + 32 * 68);
    const int tid = threadIdx.x;
    const int ty = tid >> 4, tx = tid & 15;  // thread computes 4x4 at (ty*4, tx*4)
    const int q = tid & 7, r = tid >> 3;     // loader: float4 col q, row r(+32)
    float acc[4][4] = {};

    float4 va0, va1, vw0, vw1, vb;
    {
        const int kk = k0 + q * 4;
        va0 = *(const float4*)(A + (size_t)r * lda + kk);
        va1 = *(const float4*)(A + (size_t)(r + 32) * lda + kk);
        vw0 = *(const float4*)(Wm + (size_t)(n0 + r) * ldw + kk);
        vw1 = *(const float4*)(Wm + (size_t)(n0 + r + 32) * ldw + kk);
        if (RELU_BIAS) vb = *(const float4*)(abias + kk);
    }
    for (int kc = k0; kc < k0 + klen; kc += 32) {
        float4 a0 = va0, a1 = va1;
        if (RELU_BIAS) {
            a0.x = fmaxf(a0.x + vb.x, 0.f); a0.y = fmaxf(a0.y + vb.y, 0.f);
            a0.z = fmaxf(a0.z + vb.z, 0.f); a0.w = fmaxf(a0.w + vb.w, 0.f);
            a1.x = fmaxf(a1.x + vb.x, 0.f); a1.y = fmaxf(a1.y + vb.y, 0.f);
            a1.z = fmaxf(a1.z + vb.z, 0.f); a1.w = fmaxf(a1.w + vb.w, 0.f);
        }
        As[q * 4 + 0][r] = a0.x; As[q * 4 + 1][r] = a0.y;
        As[q * 4 + 2][r] = a0.z; As[q * 4 + 3][r] = a0.w;
        As[q * 4 + 0][r + 32] = a1.x; As[q * 4 + 1][r + 32] = a1.y;
        As[q * 4 + 2][r + 32] = a1.z; As[q * 4 + 3][r + 32] = a1.w;
        Ws[q * 4 + 0][r] = vw0.x; Ws[q * 4 + 1][r] = vw0.y;
        Ws[q * 4 + 2][r] = vw0.z; Ws[q * 4 + 3][r] = vw0.w;
        Ws[q * 4 + 0][r + 32] = vw1.x; Ws[q * 4 + 1][r + 32] = vw1.y;
        Ws[q * 4 + 2][r + 32] = vw1.z; Ws[q * 4 + 3][r + 32] = vw1.w;
        __syncthreads();
        if (kc + 32 < k0 + klen) {
            const int kk = kc + 32 + q * 4;
            va0 = *(const float4*)(A + (size_t)r * lda + kk);
            va1 = *(const float4*)(A + (size_t)(r + 32) * lda + kk);
            vw0 = *(const float4*)(Wm + (size_t)(n0 + r) * ldw + kk);
            vw1 = *(const float4*)(Wm + (size_t)(n0 + r + 32) * ldw + kk);
            if (RELU_BIAS) vb = *(const float4*)(abias + kk);
        }
#pragma unroll
        for (int k = 0; k < 32; ++k) {
            const float4 a = *(const float4*)&As[k][ty * 4];
            const float4 wv = *(const float4*)&Ws[k][tx * 4];
            const float av[4] = {a.x, a.y, a.z, a.w};
            const float bv[4] = {wv.x, wv.y, wv.z, wv.w};
#pragma unroll
            for (int i = 0; i < 4; ++i)
#pragma unroll
                for (int j = 0; j < 4; ++j) acc[i][j] += av[i] * bv[j];
        }
        __syncthreads();
    }
#pragma unroll
    for (int i = 0; i < 4; ++i)
#pragma unroll
        for (int j = 0; j < 4; ++j)
            atomicAdd(Cacc + (size_t)(ty * 4 + i) * ldc + n0 + tx * 4 + j, acc[i][j]);
}

// ---------------------------------------------------------------------------
// k_loop: the entire 128-step recurrence as ONE kernel (plain launch; software
// grid barrier -> capture-safe, unlike hipLaunchCooperativeKernel).
// 256 blocks x 256 threads (<< CU capacity, so all blocks are resident).
// Per step: Phase A (LSTM + scores) -> bar -> Phase B (softmax + ctx)
//           -> bar -> Phase C (comb GEMM, zero gates) -> bar
//           -> Phase D (gates GEMM) -> bar.
// ---------------------------------------------------------------------------
__global__ __launch_bounds__(256) void k_loop(
    const int* __restrict__ tok_all, const float* __restrict__ enc,
    const float* __restrict__ emb, const float* __restrict__ Wattn,
    const float* __restrict__ battn, const float* __restrict__ Wcomb,
    const float* __restrict__ bcomb, const float* __restrict__ Wih,
    const float* __restrict__ Whh, const float* __restrict__ b_ih,
    const float* __restrict__ b_hh, float* __restrict__ Hall,
    float* __restrict__ xin, float* __restrict__ x_acc,
    float* __restrict__ gates_acc, float* __restrict__ h_buf,
    float* __restrict__ c0, float* __restrict__ c1,
    float* __restrict__ sc_all, unsigned* __restrict__ bar)
{
    __shared__ __align__(16) float smem[2 * 32 * 68];  // 17.4 KB, phase-aliased
    const int bid = blockIdx.x;
    const int tid = threadIdx.x;
    const int w = tid >> 6, lane = tid & 63;

    // token dtype sniff (int64 vs int32 device layout; values < 2^31)
    const int is64 = (tok_all[1] == 0 && tok_all[3] == 0 && tok_all[5] == 0 &&
                      tok_all[7] == 0);

    for (int t = 0; t < TT; ++t) {
        // ================= Phase A: LSTM(t-1) + attention scores ===========
        {
            const int b = bid >> 2, q = bid & 3;
            float* e_s = smem;        // [1024]
            float* h_s = smem + HH;   // [1024]

            // zero this b's comb accumulator slice (consumed in Phase D)
            x_acc[(size_t)b * HH + q * 256 + tid] = 0.f;

            const int tok = is64 ? tok_all[2 * (b * TT + t)] : tok_all[b * TT + t];
            float4 ev = ((const float4*)(emb + (size_t)tok * HH))[tid];
            ((float4*)e_s)[tid] = ev;
            if (q == 0) ((float4*)(xin + (size_t)b * 2 * HH))[tid] = ev;

            if (t == 0) {
                float4 hv = ((const float4*)(enc + (size_t)(LL - 1) * BB * HH +
                                             (size_t)b * HH))[tid];
                ((float4*)h_s)[tid] = hv;
                if (q == 0) ((float4*)(h_buf + (size_t)b * HH))[tid] = hv;
            } else {
                // all 4 sibling blocks recompute LSTM(b) (reads only old c);
                // q==0 is the single global writer (c double-buffered).
                lstm_full(gates_acc, b_ih, b_hh, (t & 1) ? c1 : c0,
                          (t & 1) ? c0 : c1, h_buf,
                          Hall + (size_t)(t - 1) * BB * HH, h_s, b, tid,
                          t == 1, q == 0);
            }
            __syncthreads();

            // scores for l in [q*64, q*64+64): wave w covers 16 l's
            const float4* es4 = (const float4*)e_s;
            const float4* hs4 = (const float4*)h_s;
            for (int i = 0; i < 16; ++i) {
                const int l = q * 64 + w * 16 + i;
                const float4* wr = (const float4*)(Wattn + (size_t)l * 2 * HH);
                float a0 = 0.f, a1 = 0.f;
#pragma unroll
                for (int it = 0; it < 4; ++it) {
                    float4 wv = wr[it * 64 + lane];
                    float4 xv = es4[it * 64 + lane];
                    a0 += wv.x * xv.x + wv.y * xv.y + wv.z * xv.z + wv.w * xv.w;
                }
#pragma unroll
                for (int it = 0; it < 4; ++it) {
                    float4 wv = wr[256 + it * 64 + lane];
                    float4 xv = hs4[it * 64 + lane];
                    a1 += wv.x * xv.x + wv.y * xv.y + wv.z * xv.z + wv.w * xv.w;
                }
                float a = a0 + a1;
#pragma unroll
                for (int o = 32; o > 0; o >>= 1) a += __shfl_down(a, o, 64);
                if (lane == 0) sc_all[(size_t)b * LL + l] = a + battn[l];
            }
        }
        grid_barrier(bar);

        // ================= Phase B: softmax + ctx ==========================
        {
            const int b = bid >> 2, hq = bid & 3;
            float* aw_s = smem;                      // [256]
            float* red = smem + 256;                 // [8]
            float4* part_s = (float4*)(smem + 272);  // [4][64] float4

            const float sv = sc_all[(size_t)b * LL + tid];
            float m = sv;
#pragma unroll
            for (int o = 32; o > 0; o >>= 1) m = fmaxf(m, __shfl_down(m, o, 64));
            if (lane == 0) red[w] = m;
            __syncthreads();
            m = fmaxf(fmaxf(red[0], red[1]), fmaxf(red[2], red[3]));
            const float ex = expf(sv - m);
            float s = ex;
#pragma unroll
            for (int o = 32; o > 0; o >>= 1) s += __shfl_down(s, o, 64);
            if (lane == 0) red[4 + w] = s;
            __syncthreads();
            const float tot = red[4] + red[5] + red[6] + red[7];
            aw_s[tid] = ex / tot;
            __syncthreads();

            // ctx cols: float4 col index col4 = hq*64+lane in [0,256);
            // wave w sums l in [w*64,w*64+64); cross-wave reduce via LDS.
            const int col4 = hq * 64 + lane;
            const float4* e4 = (const float4*)enc + (size_t)b * (HH / 4) + col4;
            float4 cacc = make_float4(0.f, 0.f, 0.f, 0.f);
#pragma unroll 8
            for (int li = 0; li < 64; ++li) {
                const int l = w * 64 + li;
                const float a = aw_s[l];
                float4 ev2 = e4[(size_t)l * (BB * HH / 4)];
                cacc.x += a * ev2.x; cacc.y += a * ev2.y;
                cacc.z += a * ev2.z; cacc.w += a * ev2.w;
            }
            part_s[w * 64 + lane] = cacc;
            __syncthreads();
            if (w == 0) {
                float4 p0 = part_s[lane];
                float4 p1 = part_s[64 + lane];
                float4 p2 = part_s[128 + lane];
                float4 p3 = part_s[192 + lane];
                float4 r4;
                r4.x = p0.x + p1.x + p2.x + p3.x;
                r4.y = p0.y + p1.y + p2.y + p3.y;
                r4.z = p0.z + p1.z + p2.z + p3.z;
                r4.w = p0.w + p1.w + p2.w + p3.w;
                ((float4*)(xin + (size_t)b * 2 * HH + HH))[col4] = r4;
            }
        }
        grid_barrier(bar);

        // ================= Phase C: comb GEMM + zero gates =================
        if (bid < 128) {  // 16 n-tiles x 8 k-splits of 256 over K=2048
            const int nt = bid >> 3, kq = bid & 7;
            gemm64x64<false>(xin, 2 * HH, nullptr, Wcomb, 2 * HH, nt * 64,
                             kq * 256, 256, x_acc, HH, smem);
        } else {          // zero gates_acc: 65536 float4 over 32768 threads
            const float4 z4 = make_float4(0.f, 0.f, 0.f, 0.f);
            float4* gz = (float4*)gates_acc;
            const int i0 = (bid - 128) * 256 + tid;
            gz[i0] = z4;
            gz[i0 + 32768] = z4;
        }
        grid_barrier(bar);

        // ================= Phase D: gates GEMM =============================
        {   // 64 n-tiles x 4 k-splits of 512 over concat-K 2048
            const int nt = bid >> 2, kq = bid & 3;
            const int k0 = kq * 512;
            if (k0 < HH)
                gemm64x64<true>(x_acc, HH, bcomb, Wih, HH, nt * 64, k0, 512,
                                gates_acc, 4 * HH, smem);
            else
                gemm64x64<false>(h_buf, HH, nullptr, Whh, HH, nt * 64, k0 - HH,
                                 512, gates_acc, 4 * HH, smem);
        }
        grid_barrier(bar);
    }

    // ================= Epilogue: final LSTM -> Hall[T-1] ===================
    if (bid < BB) {
        lstm_full(gates_acc, b_ih, b_hh, (TT & 1) ? c1 : c0, (TT & 1) ? c0 : c1,
                  h_buf, Hall + (size_t)(TT - 1) * BB * HH, nullptr, bid, tid,
                  false, true);
    }
}

// ---------------------------------------------------------------------------
// k_out: out[t,b,v] = logits - LSE over b (log_softmax over BATCH axis).
// Block: (n-tile of 128 vocab cols, one t). Tile 64x128, K=1024 fp32.
// b_out cancels exactly in log-softmax over batch -> skipped.
// ---------------------------------------------------------------------------
__global__ __launch_bounds__(256) void k_out(const float* __restrict__ Hall,
                                             const float* __restrict__ Wout,
                                             float* __restrict__ out)
{
    const int t = blockIdx.y;
    const int n0 = blockIdx.x * 128;
    const float* A = Hall + (size_t)t * BB * HH;
    __shared__ float As[32][68];
    __shared__ float Ws[32][132];
    __shared__ float Cs[64][129];
    __shared__ float lse_s[128];
    const int tid = threadIdx.x;
    const int ty = tid >> 4, tx = tid & 15;  // thread tile 4 rows x 8 cols
    const int q = tid & 7, r = tid >> 3;
    float acc[4][8] = {};

    float4 pa0, pa1, pw0, pw1, pw2, pw3;
    {
        const int kk = q * 4;
        pa0 = *(const float4*)(A + (size_t)r * HH + kk);
        pa1 = *(const float4*)(A + (size_t)(r + 32) * HH + kk);
        pw0 = *(const float4*)(Wout + (size_t)(n0 + r) * HH + kk);
        pw1 = *(const float4*)(Wout + (size_t)(n0 + r + 32) * HH + kk);
        pw2 = *(const float4*)(Wout + (size_t)(n0 + r + 64) * HH + kk);
        pw3 = *(const float4*)(Wout + (size_t)(n0 + r + 96) * HH + kk);
    }
    for (int kc = 0; kc < HH; kc += 32) {
        As[q * 4 + 0][r] = pa0.x; As[q * 4 + 1][r] = pa0.y;
        As[q * 4 + 2][r] = pa0.z; As[q * 4 + 3][r] = pa0.w;
        As[q * 4 + 0][r + 32] = pa1.x; As[q * 4 + 1][r + 32] = pa1.y;
        As[q * 4 + 2][r + 32] = pa1.z; As[q * 4 + 3][r + 32] = pa1.w;
        Ws[q * 4 + 0][r] = pw0.x; Ws[q * 4 + 1][r] = pw0.y;
        Ws[q * 4 + 2][r] = pw0.z; Ws[q * 4 + 3][r] = pw0.w;
        Ws[q * 4 + 0][r + 32] = pw1.x; Ws[q * 4 + 1][r + 32] = pw1.y;
        Ws[q * 4 + 2][r + 32] = pw1.z; Ws[q * 4 + 3][r + 32] = pw1.w;
        Ws[q * 4 + 0][r + 64] = pw2.x; Ws[q * 4 + 1][r + 64] = pw2.y;
        Ws[q * 4 + 2][r + 64] = pw2.z; Ws[q * 4 + 3][r + 64] = pw2.w;
        Ws[q * 4 + 0][r + 96] = pw3.x; Ws[q * 4 + 1][r + 96] = pw3.y;
        Ws[q * 4 + 2][r + 96] = pw3.z; Ws[q * 4 + 3][r + 96] = pw3.w;
        __syncthreads();
        if (kc + 32 < HH) {
            const int kk = kc + 32 + q * 4;
            pa0 = *(const float4*)(A + (size_t)r * HH + kk);
            pa1 = *(const float4*)(A + (size_t)(r + 32) * HH + kk);
            pw0 = *(const float4*)(Wout + (size_t)(n0 + r) * HH + kk);
            pw1 = *(const float4*)(Wout + (size_t)(n0 + r + 32) * HH + kk);
            pw2 = *(const float4*)(Wout + (size_t)(n0 + r + 64) * HH + kk);
            pw3 = *(const float4*)(Wout + (size_t)(n0 + r + 96) * HH + kk);
        }
#pragma unroll
        for (int k = 0; k < 32; ++k) {
            const float4 a = *(const float4*)&As[k][ty * 4];
            const float4 w0 = *(const float4*)&Ws[k][tx * 8];
            const float4 w1 = *(const float4*)&Ws[k][tx * 8 + 4];
            const float av[4] = {a.x, a.y, a.z, a.w};
            const float bv[8] = {w0.x, w0.y, w0.z, w0.w, w1.x, w1.y, w1.z, w1.w};
#pragma unroll
            for (int i = 0; i < 4; ++i)
#pragma unroll
                for (int j = 0; j < 8; ++j) acc[i][j] += av[i] * bv[j];
        }
        __syncthreads();
    }
#pragma unroll
    for (int i = 0; i < 4; ++i)
#pragma unroll
        for (int j = 0; j < 8; ++j) Cs[ty * 4 + i][tx * 8 + j] = acc[i][j];
    __syncthreads();

    if (tid < 128) {
        float m = -1e30f;
        for (int b = 0; b < 64; ++b) m = fmaxf(m, Cs[b][tid]);
        float s = 0.f;
        for (int b = 0; b < 64; ++b) s += expf(Cs[b][tid] - m);
        lse_s[tid] = m + logf(s);
    }
    __syncthreads();

    const int col = tid & 127, bh = tid >> 7;
    float* outp = out + (size_t)t * BB * VV + n0 + col;
    for (int b = bh; b < 64; b += 2)
        outp[(size_t)b * VV] = Cs[b][col] - lse_s[col];
}

// ---------------------------------------------------------------------------
extern "C" void kernel_launch(void* const* d_in, const int* in_sizes, int n_in,
                              void* d_out, int out_size, void* d_ws, size_t ws_size,
                              hipStream_t stream)
{
    const int* tok = (const int*)d_in[0];
    const float* enc = (const float*)d_in[1];
    const float* emb = (const float*)d_in[2];
    const float* W_attn = (const float*)d_in[3];
    const float* b_attn = (const float*)d_in[4];
    const float* W_comb = (const float*)d_in[5];
    const float* b_comb = (const float*)d_in[6];
    const float* W_ih = (const float*)d_in[7];
    const float* W_hh = (const float*)d_in[8];
    const float* b_ih = (const float*)d_in[9];
    const float* b_hh = (const float*)d_in[10];
    const float* W_out = (const float*)d_in[11];
    // d_in[12] = b_out: constant over batch -> cancels in log_softmax(axis=batch)
    float* out = (float*)d_out;
    float* ws = (float*)d_ws;

    const size_t n_Hall = (size_t)TT * BB * HH;   // 8388608
    const size_t n_xin = (size_t)BB * 2 * HH;     // 131072
    const size_t n_xacc = (size_t)BB * HH;        // 65536
    const size_t n_gates = (size_t)BB * 4 * HH;   // 262144
    const size_t n_bh = (size_t)BB * HH;          // 65536 (h, c0, c1 each)
    const size_t n_sc = (size_t)BB * LL;          // 16384
    const size_t n_bar = 2048;                    // barrier state (u32)
    const size_t needed =
        (n_Hall + n_xin + n_xacc + n_gates + 3 * n_bh + n_sc + n_bar) * 4;
    if (ws_size < needed) return;  // would corrupt; bail (visible as incorrect)

    float* H_all = ws;
    float* xin = H_all + n_Hall;
    float* x_acc = xin + n_xin;
    float* gates_acc = x_acc + n_xacc;
    float* h_buf = gates_acc + n_gates;
    float* c0 = h_buf + n_bh;
    float* c1 = c0 + n_bh;
    float* sc_all = c1 + n_bh;
    unsigned* bar = (unsigned*)(sc_all + n_sc);

    // reset barrier state (stream-ordered, capture/replay-safe)
    hipMemsetAsync(bar, 0, n_bar * 4, stream);

    k_loop<<<NBLK, 256, 0, stream>>>(tok, enc, emb, W_attn, b_attn, W_comb,
                                     b_comb, W_ih, W_hh, b_ih, b_hh, H_all,
                                     xin, x_acc, gates_acc, h_buf, c0, c1,
                                     sc_all, bar);
    k_out<<<dim3(125, 128), 256, 0, stream>>>(H_all, W_out, out);
}